// Round 10
// baseline (1171.198 us; speedup 1.0000x reference)
//
#include <hip/hip_runtime.h>

// TopK-and-scatter: out[r,c] = x[r,c] if x[r,c] is among the top-64 of row r
// (ties at threshold broken by LOWEST column index, matching lax.top_k), else 0.
// R10 = R6's register-resident row pipeline, FIXED: __launch_bounds__(1024,4)
// gives the compiler a 128-VGPR budget (R6's silent 64-VGPR default spilled
// raw[]+key[] to scratch and buried the experiment). One block per CU, RPB=32
// rows per block; while row i is selected/written, row i+1's 8 float4 loads
// are in flight (issued into the just-freed raw[] registers, chunk by chunk).
// All fast-path barriers are lgkm-only raw s_barrier (R6/R7-proven), so the
// prefetch loads are never drained by a barrier. Select machinery = R8's:
// positive-only 12-bit histogram (bits[30:19]) -> shuffle suffix scan ->
// crossing-bin candidates packed u64 -> fused-rank vector write.
// Exact bitwise-search slow path (block-uniform, never taken for normal data).

typedef float f32x4 __attribute__((ext_vector_type(4)));
typedef unsigned int u32;
typedef unsigned long long u64;
typedef u32 u32x4 __attribute__((ext_vector_type(4)));

#define TPB   1024
#define COLS  32768
#define EPT   32
#define KSEL  64u
#define CAP   2048u
#define RPB   32

// LDS-only barrier: orders LDS ops across the block WITHOUT draining vmcnt,
// so in-flight global loads survive select+write. (R6/R7-validated pattern.)
__device__ __forceinline__ void ldsBarrier() {
    asm volatile("s_waitcnt lgkmcnt(0)" ::: "memory");
    __builtin_amdgcn_s_barrier();
    asm volatile("" ::: "memory");
}

__device__ __forceinline__ u32 blockSum(u32 v, u32* wtot, int lane, int wid)
{
    #pragma unroll
    for (int off = 32; off >= 1; off >>= 1) v += __shfl_down(v, off);
    if (lane == 0) wtot[wid] = v;
    __syncthreads();
    u32 t = 0;
    #pragma unroll
    for (int w = 0; w < 16; ++w) t += wtot[w];
    __syncthreads();
    return t;
}

__global__ __launch_bounds__(TPB, 4) void topk_scatter_kernel(
    const float* __restrict__ x, float* __restrict__ out, int totalRows)
{
    __shared__ u32 hist[4096];            // 16 KB
    __shared__ u64 candPk[CAP];           // 16 KB
    __shared__ u32 wtot[16];
    __shared__ int sBin;
    __shared__ u32 sAbove;
    __shared__ u32 candN;

    const int tid  = threadIdx.x;
    const int lane = tid & 63;
    const int wid  = tid >> 6;
    const int r0   = blockIdx.x * RPB;
    if (r0 >= totalRows) return;

    // ---- prologue: zero hist, issue row r0 loads ----
    ((u32x4*)hist)[tid] = (u32x4)(0u);
    if (tid == 0) { sBin = -1; candN = 0u; }
    f32x4 raw[8];
    {
        const f32x4* __restrict__ xr = (const f32x4*)(x + (long long)r0 * COLS);
        #pragma unroll
        for (int j = 0; j < 8; ++j) raw[j] = xr[j * TPB + tid];
    }
    ldsBarrier();                                      // zeros visible; loads fly

    #pragma unroll 1
    for (int i = 0; i < RPB; ++i) {
        const int row = r0 + i;
        if (row >= totalRows) break;                   // block-uniform
        const bool haveNext = (i + 1 < RPB) && (row + 1 < totalRows);

        // ---- convert raw -> keys chunk-by-chunk; refill raw[j] with row i+1
        //      (compiler inserts counted vmcnt waits per chunk; the new loads
        //      go straight back into the freed registers) ----
        u32 key[EPT];
        #pragma unroll
        for (int j = 0; j < 8; ++j) {
            const f32x4 v = raw[j];
            #pragma unroll
            for (int l = 0; l < 4; ++l) {
                const u32 b = __float_as_uint(v[l]);
                key[j * 4 + l] = b ^ ((u32)((int)b >> 31) | 0x80000000u);
            }
            if (haveNext) {
                const f32x4* __restrict__ xn =
                    (const f32x4*)(x + (long long)(row + 1) * COLS);
                raw[j] = xn[j * TPB + tid];
            }
        }

        // ---- positive-only histogram: bins = bits [30:19] ----
        #pragma unroll
        for (int e = 0; e < EPT; ++e) {
            const u32 k = key[e];
            if (k & 0x80000000u) atomicAdd(&hist[(k & 0x7fffffffu) >> 19], 1u);
        }
        ldsBarrier();                                  // B: hist complete

        // ---- suffix scan; thread owns bins [4*tid,4*tid+4); zero after read;
        //      tid0 resets sBin/candN here (2 barriers from any reader) ----
        u32 need = KSEL;
        {
            const u32x4 h = ((const u32x4*)hist)[tid];
            ((u32x4*)hist)[tid] = (u32x4)(0u);         // ready for next row
            if (tid == 0) { sBin = -1; candN = 0u; }   // safe: ordered by C, D
            const u32 ls3 = h[3];
            const u32 ls2 = h[2] + ls3;
            const u32 ls1 = h[1] + ls2;
            const u32 ls0 = h[0] + ls1;
            u32 v = ls0;
            #pragma unroll
            for (int off = 1; off < 64; off <<= 1) {
                const u32 t = __shfl_down(v, off);
                if (lane + off < 64) v += t;
            }
            if (lane == 0) wtot[wid] = v;
            ldsBarrier();                              // C: wtot + resets ready
            u32 tailWaves = 0u;
            for (int w = wid + 1; w < 16; ++w) tailWaves += wtot[w];
            const u32 thrTail = tailWaves + (v - ls0);
            const u32 S0 = ls0 + thrTail, S1 = ls1 + thrTail, S2 = ls2 + thrTail,
                      S3 = ls3 + thrTail, S4 = thrTail;
            if (S0 >= need && S1 < need) { sBin = 4 * tid + 0; sAbove = S1; }
            if (S1 >= need && S2 < need) { sBin = 4 * tid + 1; sAbove = S2; }
            if (S2 >= need && S3 < need) { sBin = 4 * tid + 2; sAbove = S3; }
            if (S3 >= need && S4 < need) { sBin = 4 * tid + 3; sAbove = S4; }
            ldsBarrier();                              // D: crossing known
        }
        const int b1s = sBin;                          // snapshot immediately
        const u32 above = sAbove;
        bool fast = (b1s >= 0);
        u32 b1 = 0, C = 0;

        if (fast) {
            b1 = (u32)b1s;
            need = KSEL - above;                       // 1 <= need <= count(b1)
            // ---- collect crossing-bin candidates, packed (key desc, col asc) ----
            #pragma unroll
            for (int e = 0; e < EPT; ++e) {
                const u32 k = key[e];
                if ((k & 0x80000000u) && ((k & 0x7fffffffu) >> 19) == b1) {
                    const u32 p = atomicAdd(&candN, 1u);
                    if (p < CAP) {
                        const u32 col = (u32)(((e >> 2) * TPB + tid) * 4 + (e & 3));
                        candPk[p] = ((u64)k << 32) | (u32)(~col);
                    }
                }
            }
            ldsBarrier();                              // E: candidates ready
            C = candN;                                 // snapshot immediately
            fast = (C <= CAP);
        }

        f32x4* __restrict__ orow = (f32x4*)(out + (long long)row * COLS);

        if (fast) {
            // ---- fused write: per-thread exact rank for own b1 elements ----
            #pragma unroll
            for (int j = 0; j < 8; ++j) {
                f32x4 o;
                #pragma unroll
                for (int l = 0; l < 4; ++l) {
                    const u32 k = key[j * 4 + l];
                    bool sel = false;
                    if (k & 0x80000000u) {
                        const u32 kb = (k & 0x7fffffffu) >> 19;
                        if (kb > b1) sel = true;
                        else if (kb == b1) {
                            const u32 col = (u32)((j * TPB + tid) * 4 + l);
                            const u64 me = ((u64)k << 32) | (u32)(~col);
                            u32 r = 0;
                            for (u32 q = 0; q < C; ++q)    // LDS b64 broadcast
                                r += (candPk[q] > me) ? 1u : 0u;
                            sel = (r < need);
                        }
                    }
                    o[l] = sel ? __uint_as_float(k ^ 0x80000000u) : 0.0f;
                }
                orow[j * TPB + tid] = o;
            }
        } else {
            // ---- exact slow path (any input): bitwise searches ----
            u32 pfx = 0u;
            for (int bit = 31; bit >= 0; --bit) {
                const u32 trial = pfx | (1u << bit);
                u32 loc = 0u;
                #pragma unroll
                for (int e = 0; e < EPT; ++e) loc += (key[e] >= trial) ? 1u : 0u;
                if (blockSum(loc, wtot, lane, wid) >= KSEL) pfx = trial;
            }
            const u32 T = pfx;                         // 64th largest key
            u32 loc = 0u;
            #pragma unroll
            for (int e = 0; e < EPT; ++e) loc += (key[e] > T) ? 1u : 0u;
            const u32 needEq = KSEL - blockSum(loc, wtot, lane, wid);
            u32 cv = 0u;
            for (int bit = 14; bit >= 0; --bit) {
                const u32 trial = cv | (1u << bit);
                u32 l2 = 0u;
                #pragma unroll
                for (int e = 0; e < EPT; ++e) {
                    const u32 col = (u32)(((e >> 2) * TPB + tid) * 4 + (e & 3));
                    l2 += (key[e] == T && col < trial) ? 1u : 0u;
                }
                if (blockSum(l2, wtot, lane, wid) < needEq) cv = trial;
            }
            const u32 colT = cv;                       // needEq-th smallest eq col
            #pragma unroll
            for (int j = 0; j < 8; ++j) {
                f32x4 o;
                #pragma unroll
                for (int l = 0; l < 4; ++l) {
                    const u32 k = key[j * 4 + l];
                    const u32 col = (u32)((j * TPB + tid) * 4 + l);
                    const bool sel = (k > T) || (k == T && col <= colT);
                    const float val =
                        __uint_as_float((k & 0x80000000u) ? (k ^ 0x80000000u) : ~k);
                    o[l] = sel ? val : 0.0f;
                }
                orow[j * TPB + tid] = o;
            }
        }
    }
}

extern "C" void kernel_launch(void* const* d_in, const int* in_sizes, int n_in,
                              void* d_out, int out_size, void* d_ws, size_t ws_size,
                              hipStream_t stream)
{
    (void)n_in; (void)out_size; (void)d_ws; (void)ws_size;
    const float* x = (const float*)d_in[0];
    float* out = (float*)d_out;
    const int rows = in_sizes[0] / COLS;
    const int grid = (rows + RPB - 1) / RPB;
    topk_scatter_kernel<<<dim3(grid), dim3(TPB), 0, stream>>>(x, out, rows);
}

// Round 11
// 647.131 us; speedup vs baseline: 1.8098x; 1.8098x over previous
//
#include <hip/hip_runtime.h>

// TopK-and-scatter: out[r,c] = x[r,c] if x[r,c] is among the top-64 of row r
// (ties at threshold broken by LOWEST column index, matching lax.top_k), else 0.
// R11 = R8 chassis (one row per 1024-thread block, 2 blocks/CU, loads->regs,
// 4096-bin positive histogram, shuffle suffix scan, packed-u64 candidates,
// fused-rank vector write) with ZERO key conversion on the fast path:
// positive floats order identically as raw uint bits (signed compare excludes
// negatives), and the stored value is the raw bits themselves. Histogram bins
// = bits[30:19] of values with (int)b>0. Slow path (no positive crossing or
// candidate overflow; never taken for normal data) computes canonical keys on
// demand — exact for any input including ties, negatives, NaN/Inf edge cases.

typedef float f32x4 __attribute__((ext_vector_type(4)));
typedef unsigned int u32;
typedef unsigned long long u64;
typedef u32 u32x4 __attribute__((ext_vector_type(4)));

#define TPB   1024
#define COLS  32768
#define EPT   32
#define KSEL  64u
#define CAP   2048u

__device__ __forceinline__ u32 blockSum(u32 v, u32* wtot, int lane, int wid)
{
    #pragma unroll
    for (int off = 32; off >= 1; off >>= 1) v += __shfl_down(v, off);
    if (lane == 0) wtot[wid] = v;
    __syncthreads();
    u32 t = 0;
    #pragma unroll
    for (int w = 0; w < 16; ++w) t += wtot[w];
    __syncthreads();
    return t;
}

__device__ __forceinline__ u32 toKey(u32 b)
{
    return b ^ ((u32)((int)b >> 31) | 0x80000000u);
}

__global__ __launch_bounds__(TPB) void topk_scatter_kernel(
    const float* __restrict__ x, float* __restrict__ out)
{
    __shared__ u32 hist[4096];            // 16 KB
    __shared__ u64 candPk[CAP];           // 16 KB
    __shared__ u32 wtot[16];
    __shared__ int sBin;
    __shared__ u32 sAbove;
    __shared__ u32 candN;

    const int tid  = threadIdx.x;
    const int lane = tid & 63;
    const int wid  = tid >> 6;

    const long long row = blockIdx.x;
    const u32x4* __restrict__ xrow = (const u32x4*)(x + row * (long long)COLS);
    u32x4* __restrict__ orow       = (u32x4*)(out + row * (long long)COLS);

    // zero histogram + counters (ordered by barrier A)
    ((u32x4*)hist)[tid] = (u32x4)(0u);
    if (tid == 0) { sBin = -1; candN = 0u; }

    // ---- load row into registers as RAW BITS (8 loads in flight) ----
    u32 b[EPT];
    #pragma unroll
    for (int j = 0; j < 8; ++j) {
        const u32x4 v = xrow[j * TPB + tid];
        #pragma unroll
        for (int l = 0; l < 4; ++l) b[j * 4 + l] = v[l];
    }
    __syncthreads();                                   // A: zeros visible

    // ---- positive-only histogram: bins = bits [30:19] of (int)b > 0 ----
    #pragma unroll
    for (int e = 0; e < EPT; ++e) {
        const u32 k = b[e];
        if ((int)k > 0) atomicAdd(&hist[k >> 19], 1u); // sign=0 -> bin 0..4095
    }
    __syncthreads();                                   // B: hist complete

    u32 need = KSEL;

    // ---- suffix scan: thread owns bins [4*tid, 4*tid+4) ----
    {
        const u32x4 h = ((const u32x4*)hist)[tid];
        const u32 ls3 = h[3];
        const u32 ls2 = h[2] + ls3;
        const u32 ls1 = h[1] + ls2;
        const u32 ls0 = h[0] + ls1;
        u32 v = ls0;                                   // wave suffix scan (shfl)
        #pragma unroll
        for (int off = 1; off < 64; off <<= 1) {
            const u32 t = __shfl_down(v, off);
            if (lane + off < 64) v += t;
        }
        if (lane == 0) wtot[wid] = v;
        __syncthreads();                               // C: wtot ready
        u32 tailWaves = 0u;
        for (int w = wid + 1; w < 16; ++w) tailWaves += wtot[w];
        const u32 thrTail = tailWaves + (v - ls0);
        const u32 S0 = ls0 + thrTail, S1 = ls1 + thrTail, S2 = ls2 + thrTail,
                  S3 = ls3 + thrTail, S4 = thrTail;
        if (S0 >= need && S1 < need) { sBin = 4 * tid + 0; sAbove = S1; }
        if (S1 >= need && S2 < need) { sBin = 4 * tid + 1; sAbove = S2; }
        if (S2 >= need && S3 < need) { sBin = 4 * tid + 2; sAbove = S3; }
        if (S3 >= need && S4 < need) { sBin = 4 * tid + 3; sAbove = S4; }
        __syncthreads();                               // D: crossing known
    }
    const int b1s = sBin;                              // snapshot
    const u32 above = sAbove;
    bool fast = (b1s >= 0);
    u32 b1 = 0, C = 0;

    if (fast) {
        b1 = (u32)b1s;
        need = KSEL - above;                           // 1 <= need <= count(b1)
        // ---- collect crossing-bin candidates, packed (bits desc, col asc) ----
        #pragma unroll
        for (int e = 0; e < EPT; ++e) {
            const u32 k = b[e];
            if ((int)k > 0 && (k >> 19) == b1) {
                const u32 p = atomicAdd(&candN, 1u);
                if (p < CAP) {
                    const u32 col = (u32)(((e >> 2) * TPB + tid) * 4 + (e & 3));
                    candPk[p] = ((u64)k << 32) | (u32)(~col);
                }
            }
        }
        __syncthreads();                               // E: candidates ready
        C = candN;                                     // snapshot
        fast = (C <= CAP);
    }

    if (fast) {
        // ---- fused write: raw bits pass through, no conversion anywhere ----
        #pragma unroll
        for (int j = 0; j < 8; ++j) {
            u32x4 o;
            #pragma unroll
            for (int l = 0; l < 4; ++l) {
                const u32 k = b[j * 4 + l];
                bool sel = false;
                if ((int)k > 0) {
                    const u32 kb = k >> 19;
                    if (kb > b1) sel = true;
                    else if (kb == b1) {
                        const u32 col = (u32)((j * TPB + tid) * 4 + l);
                        const u64 me = ((u64)k << 32) | (u32)(~col);
                        u32 r = 0;
                        for (u32 q = 0; q < C; ++q)        // LDS b64 broadcast
                            r += (candPk[q] > me) ? 1u : 0u;
                        sel = (r < need);
                    }
                }
                o[l] = sel ? k : 0u;
            }
            orow[j * TPB + tid] = o;
        }
    } else {
        // ---- exact slow path (any input): bitwise searches on full keys ----
        u32 pfx = 0u;
        for (int bit = 31; bit >= 0; --bit) {
            const u32 trial = pfx | (1u << bit);
            u32 loc = 0u;
            #pragma unroll
            for (int e = 0; e < EPT; ++e) loc += (toKey(b[e]) >= trial) ? 1u : 0u;
            if (blockSum(loc, wtot, lane, wid) >= KSEL) pfx = trial;
        }
        const u32 T = pfx;                             // 64th largest key
        u32 loc = 0u;
        #pragma unroll
        for (int e = 0; e < EPT; ++e) loc += (toKey(b[e]) > T) ? 1u : 0u;
        const u32 needEq = KSEL - blockSum(loc, wtot, lane, wid);
        u32 cv = 0u;
        for (int bit = 14; bit >= 0; --bit) {
            const u32 trial = cv | (1u << bit);
            u32 l2 = 0u;
            #pragma unroll
            for (int e = 0; e < EPT; ++e) {
                const u32 col = (u32)(((e >> 2) * TPB + tid) * 4 + (e & 3));
                l2 += (toKey(b[e]) == T && col < trial) ? 1u : 0u;
            }
            if (blockSum(l2, wtot, lane, wid) < needEq) cv = trial;
        }
        const u32 colT = cv;                           // needEq-th smallest eq col
        #pragma unroll
        for (int j = 0; j < 8; ++j) {
            u32x4 o;
            #pragma unroll
            for (int l = 0; l < 4; ++l) {
                const u32 k = toKey(b[j * 4 + l]);
                const u32 col = (u32)((j * TPB + tid) * 4 + l);
                const bool sel = (k > T) || (k == T && col <= colT);
                o[l] = sel ? b[j * 4 + l] : 0u;
            }
            orow[j * TPB + tid] = o;
        }
    }
}

extern "C" void kernel_launch(void* const* d_in, const int* in_sizes, int n_in,
                              void* d_out, int out_size, void* d_ws, size_t ws_size,
                              hipStream_t stream)
{
    (void)n_in; (void)out_size; (void)d_ws; (void)ws_size;
    const float* x = (const float*)d_in[0];
    float* out = (float*)d_out;
    const int rows = in_sizes[0] / COLS;
    topk_scatter_kernel<<<dim3(rows), dim3(TPB), 0, stream>>>(x, out);
}

// Round 12
// 449.044 us; speedup vs baseline: 2.6082x; 1.4411x over previous
//
#include <hip/hip_runtime.h>

// TopK-and-scatter: out[r,c] = x[r,c] if x[r,c] is among the top-64 of row r
// (ties at threshold broken by LOWEST column index, matching lax.top_k), else 0.
// R12: two-pass streaming, 256-thread blocks (one row each), ~6 blocks/CU.
// Pass A: stream row, positive-only 2048-bin histogram (bits[30:20] of raw
// IEEE bits; positives order as unsigned ints). Scan -> crossing bin b1.
// Pass B: stream row AGAIN (L2/L3-hot: active set ~192 MB < 256 MB L3),
// write every element (value if bin>b1, else 0), collect bin==b1 candidates
// packed ((bits<<32)|~col). Final: exact composite rank over candidates,
// rewrite the <=need selected borderline values. No big register arrays ->
// no spill cliff; overlap comes from 6 independent blocks per CU in
// different phases instead of a lockstep pair.
// Exact bitwise-search slow path (streams the row; block-uniform; only for
// pathological inputs: <64 positives or >CAP candidates).

typedef unsigned int u32;
typedef unsigned long long u64;
typedef u32 u32x4 __attribute__((ext_vector_type(4)));

#define TPB   256
#define COLS  32768
#define VPT   32          // u32x4 vectors per thread (32*4*256 = 32768)
#define NB    2048        // histogram bins: bits [30:20] of positive values
#define KSEL  64u
#define CAP   2048u

__device__ __forceinline__ u32 toKey(u32 b) {
    return b ^ ((u32)((int)b >> 31) | 0x80000000u);
}

__device__ __forceinline__ u32 blockSum(u32 v, volatile u32* wt, int lane, int wid)
{
    #pragma unroll
    for (int off = 32; off >= 1; off >>= 1) v += __shfl_down(v, off);
    if (lane == 0) wt[wid] = v;
    __syncthreads();
    u32 t = 0;
    #pragma unroll
    for (int w = 0; w < 4; ++w) t += wt[w];
    __syncthreads();
    return t;
}

__global__ __launch_bounds__(TPB, 6) void topk_scatter_kernel(
    const float* __restrict__ x, float* __restrict__ out)
{
    __shared__ u32 hist[NB];              // 8 KB
    __shared__ u64 candPk[CAP];           // 16 KB
    __shared__ u32 wtot[4];
    __shared__ int sBin;
    __shared__ u32 sAbove;
    __shared__ u32 candN;

    const int tid  = threadIdx.x;
    const int lane = tid & 63;
    const int wid  = tid >> 6;

    const long long row = blockIdx.x;
    const u32x4* __restrict__ xrow = (const u32x4*)(x + row * (long long)COLS);
    u32x4* __restrict__ orow       = (u32x4*)(out + row * (long long)COLS);
    u32*   __restrict__ orowU      = (u32*)(out + row * (long long)COLS);

    // zero histogram + flags
    ((u32x4*)hist)[tid]       = (u32x4)(0u);
    ((u32x4*)hist)[tid + TPB] = (u32x4)(0u);
    if (tid == 0) { sBin = -1; candN = 0u; }
    __syncthreads();                                   // A: zeros visible

    // ---- Pass A: stream row, histogram positives (groups of 8 vectors) ----
    #pragma unroll 1
    for (int g = 0; g < 4; ++g) {
        u32x4 v[8];
        #pragma unroll
        for (int j = 0; j < 8; ++j) v[j] = xrow[(g * 8 + j) * TPB + tid];
        #pragma unroll
        for (int j = 0; j < 8; ++j) {
            #pragma unroll
            for (int l = 0; l < 4; ++l) {
                const u32 k = v[j][l];
                if ((int)k > 0) atomicAdd(&hist[k >> 20], 1u);
            }
        }
    }
    __syncthreads();                                   // B: hist complete

    u32 need = KSEL;

    // ---- suffix scan: thread owns bins [8*tid, 8*tid+8) ----
    {
        const u32x4 h0 = ((const u32x4*)hist)[2 * tid];
        const u32x4 h1 = ((const u32x4*)hist)[2 * tid + 1];
        u32 ls[9];
        ls[8] = 0u;
        ls[7] = h1[3];
        ls[6] = h1[2] + ls[7];
        ls[5] = h1[1] + ls[6];
        ls[4] = h1[0] + ls[5];
        ls[3] = h0[3] + ls[4];
        ls[2] = h0[2] + ls[3];
        ls[1] = h0[1] + ls[2];
        ls[0] = h0[0] + ls[1];
        u32 v = ls[0];                                 // wave suffix scan (shfl)
        #pragma unroll
        for (int off = 1; off < 64; off <<= 1) {
            const u32 t = __shfl_down(v, off);
            if (lane + off < 64) v += t;
        }
        if (lane == 0) wtot[wid] = v;
        __syncthreads();                               // C: wtot ready
        u32 tailWaves = 0u;
        #pragma unroll
        for (int w = 0; w < 4; ++w) if (w > wid) tailWaves += wtot[w];
        const u32 thrTail = tailWaves + (v - ls[0]);
        #pragma unroll
        for (int i = 0; i < 8; ++i) {
            const u32 Si  = ls[i]     + thrTail;
            const u32 Si1 = ls[i + 1] + thrTail;
            if (Si >= need && Si1 < need) { sBin = 8 * tid + i; sAbove = Si1; }
        }
        __syncthreads();                               // D: crossing known
    }
    const int b1s  = sBin;                             // snapshot
    const u32 above = sAbove;
    bool fast = (b1s >= 0);
    const u32 b1 = (u32)b1s;                           // valid only if fast
    const u32 needB = KSEL - above;                    // valid only if fast
    u32 C = 0;

    if (fast) {
        // ---- Pass B: re-read (cache-hot), write, collect candidates ----
        #pragma unroll 1
        for (int g = 0; g < 4; ++g) {
            u32x4 v[8];
            #pragma unroll
            for (int j = 0; j < 8; ++j) v[j] = xrow[(g * 8 + j) * TPB + tid];
            #pragma unroll
            for (int j = 0; j < 8; ++j) {
                u32x4 o;
                #pragma unroll
                for (int l = 0; l < 4; ++l) {
                    const u32 k = v[j][l];
                    bool sel = false;
                    if ((int)k > 0) {
                        const u32 kb = k >> 20;
                        if (kb > b1) sel = true;
                        else if (kb == b1) {
                            const u32 p = atomicAdd(&candN, 1u);
                            const u32 col =
                                (u32)(((g * 8 + j) * TPB + tid) * 4 + l);
                            if (p < CAP)
                                candPk[p] = ((u64)k << 32) | (u32)(~col);
                        }
                    }
                    o[l] = sel ? k : 0u;
                }
                __builtin_nontemporal_store(o, &orow[(g * 8 + j) * TPB + tid]);
            }
        }
        __syncthreads();                               // E: stores drained, cands ready
        C = candN;
        fast = (C <= CAP);
    }

    if (fast) {
        // ---- exact rank over candidates; rewrite selected borderline ----
        for (u32 i = tid; i < C; i += TPB) {
            const u64 pk = candPk[i];
            u32 r = 0;
            for (u32 q = 0; q < C; ++q) r += (candPk[q] > pk) ? 1u : 0u;
            if (r < needB) {
                const u32 col = ~((u32)pk);
                orowU[col] = (u32)(pk >> 32);
            }
        }
    } else {
        // ---- exact slow path: bitwise searches, streaming re-reads ----
        u32 pfx = 0u;
        for (int bit = 31; bit >= 0; --bit) {
            const u32 trial = pfx | (1u << bit);
            u32 loc = 0u;
            #pragma unroll 1
            for (int m = 0; m < VPT; ++m) {
                const u32x4 v = xrow[m * TPB + tid];
                #pragma unroll
                for (int l = 0; l < 4; ++l)
                    loc += (toKey(v[l]) >= trial) ? 1u : 0u;
            }
            if (blockSum(loc, wtot, lane, wid) >= KSEL) pfx = trial;
        }
        const u32 T = pfx;                             // 64th largest key
        u32 loc = 0u;
        #pragma unroll 1
        for (int m = 0; m < VPT; ++m) {
            const u32x4 v = xrow[m * TPB + tid];
            #pragma unroll
            for (int l = 0; l < 4; ++l) loc += (toKey(v[l]) > T) ? 1u : 0u;
        }
        const u32 needEq = KSEL - blockSum(loc, wtot, lane, wid);
        u32 cv = 0u;
        for (int bit = 14; bit >= 0; --bit) {
            const u32 trial = cv | (1u << bit);
            u32 l2 = 0u;
            #pragma unroll 1
            for (int m = 0; m < VPT; ++m) {
                const u32x4 v = xrow[m * TPB + tid];
                #pragma unroll
                for (int l = 0; l < 4; ++l) {
                    const u32 col = (u32)((m * TPB + tid) * 4 + l);
                    l2 += (toKey(v[l]) == T && col < trial) ? 1u : 0u;
                }
            }
            if (blockSum(l2, wtot, lane, wid) < needEq) cv = trial;
        }
        const u32 colT = cv;                           // needEq-th smallest eq col
        #pragma unroll 1
        for (int m = 0; m < VPT; ++m) {
            const u32x4 v = xrow[m * TPB + tid];
            u32x4 o;
            #pragma unroll
            for (int l = 0; l < 4; ++l) {
                const u32 k = toKey(v[l]);
                const u32 col = (u32)((m * TPB + tid) * 4 + l);
                const bool sel = (k > T) || (k == T && col <= colT);
                o[l] = sel ? v[l] : 0u;
            }
            orow[m * TPB + tid] = o;
        }
    }
}

extern "C" void kernel_launch(void* const* d_in, const int* in_sizes, int n_in,
                              void* d_out, int out_size, void* d_ws, size_t ws_size,
                              hipStream_t stream)
{
    (void)n_in; (void)out_size; (void)d_ws; (void)ws_size;
    const float* x = (const float*)d_in[0];
    float* out = (float*)d_out;
    const int rows = in_sizes[0] / COLS;
    topk_scatter_kernel<<<dim3(rows), dim3(TPB), 0, stream>>>(x, out);
}